// Round 2
// baseline (149.216 us; speedup 1.0000x reference)
//
#include <hip/hip_runtime.h>

#define BATCH 16
#define NN 1024
#define FF 128

typedef __attribute__((ext_vector_type(8))) short bf16x8;
typedef __attribute__((ext_vector_type(4))) float f32x4;

__device__ __forceinline__ unsigned short f2bf(float x) {
  unsigned u = __float_as_uint(x);
  u += 0x7fff + ((u >> 16) & 1);   // round-to-nearest-even
  return (unsigned short)(u >> 16);
}
__device__ __forceinline__ float bf2f(unsigned short b) {
  return __uint_as_float(((unsigned)b) << 16);
}
__device__ __forceinline__ bf16x8 cvt8(float4 a, float4 b) {
  bf16x8 r;
  r[0] = (short)f2bf(a.x); r[1] = (short)f2bf(a.y);
  r[2] = (short)f2bf(a.z); r[3] = (short)f2bf(a.w);
  r[4] = (short)f2bf(b.x); r[5] = (short)f2bf(b.y);
  r[6] = (short)f2bf(b.z); r[7] = (short)f2bf(b.w);
  return r;
}

// ---------------------------------------------------------------------------
// K1: deg[b,n] = 1 + sum_m A[b,n,m];  d = rsqrt(deg).  One wave per row.
// Tail blocks (>=4096) also build Wt[g][f] = bf16(W[f][g]).
// ---------------------------------------------------------------------------
__global__ __launch_bounds__(256) void k_deg(const float* __restrict__ A,
                                             const float* __restrict__ W,
                                             float* __restrict__ d,
                                             unsigned short* __restrict__ Wt) {
  if (blockIdx.x >= 4096) {
    int id = (blockIdx.x - 4096) * 256 + threadIdx.x;
    int g = id >> 7, f = id & 127;
    Wt[g * 128 + f] = f2bf(W[f * 128 + g]);
    return;
  }
  int row  = blockIdx.x * 4 + (threadIdx.x >> 6);
  int lane = threadIdx.x & 63;
  const float4* Ar = (const float4*)(A + (size_t)row * NN);
  float s = 0.f;
#pragma unroll
  for (int i = 0; i < 4; ++i) {
    float4 v = Ar[lane + i * 64];
    s += (v.x + v.y) + (v.z + v.w);
  }
#pragma unroll
  for (int off = 32; off > 0; off >>= 1) s += __shfl_down(s, off, 64);
  if (lane == 0) d[row] = rsqrtf(s + 1.0f);
}

// ---------------------------------------------------------------------------
// K2: Yt[b][g][m] = bf16( d[b,m] * sum_f X[b,m,f] * W[f,g] )
// Wave-centric, no LDS, no barriers. Each wave: 16 m-rows x 128 g, K=128.
// Grid: 256 blocks x 4 waves = 1024 waves = 16 b x 64 m-tiles.
// ---------------------------------------------------------------------------
__global__ __launch_bounds__(256) void k_xw(const float* __restrict__ X,
                                            const unsigned short* __restrict__ Wt,
                                            const float* __restrict__ d,
                                            unsigned short* __restrict__ Yt) {
  int t = threadIdx.x;
  int wave = t >> 6, lane = t & 63;
  int quad = lane >> 4, l16 = lane & 15;
  int b  = blockIdx.x >> 4;
  int m0 = ((blockIdx.x & 15) * 4 + wave) * 16;

  const float* Xp = X + ((size_t)(b * NN + m0 + l16) * FF) + quad * 8;

  f32x4 acc[8];
#pragma unroll
  for (int ct = 0; ct < 8; ++ct) acc[ct] = (f32x4){0.f, 0.f, 0.f, 0.f};

#pragma unroll
  for (int k0 = 0; k0 < 128; k0 += 32) {
    float4 a0 = *(const float4*)(Xp + k0);
    float4 a1 = *(const float4*)(Xp + k0 + 4);
    bf16x8 af = cvt8(a0, a1);
#pragma unroll
    for (int ct = 0; ct < 8; ++ct) {
      bf16x8 wf = *(const bf16x8*)(Wt + (ct * 16 + l16) * 128 + k0 + quad * 8);
      acc[ct] = __builtin_amdgcn_mfma_f32_16x16x32_bf16(af, wf, acc[ct], 0, 0, 0);
    }
  }

  // C/D: row(m) = quad*4+reg, col(g) = l16. Store transposed: Yt[b][g][m].
  int mb = m0 + quad * 4;
  float4 d4 = *(const float4*)(d + b * NN + mb);
#pragma unroll
  for (int ct = 0; ct < 8; ++ct) {
    int g = ct * 16 + l16;
    ushort4 p;
    p.x = f2bf(d4.x * acc[ct][0]);
    p.y = f2bf(d4.y * acc[ct][1]);
    p.z = f2bf(d4.z * acc[ct][2]);
    p.w = f2bf(d4.w * acc[ct][3]);
    *(ushort4*)(Yt + (size_t)(b * 128 + g) * NN + mb) = p;
  }
}

// ---------------------------------------------------------------------------
// K3: out[b,n,g] = d[n] * ( sum_m A[b,n,m]*Yt[b,g,m] + Yt[b,g,n] )
// Wave-centric, no LDS, no barriers. Each wave: 16 n-rows x 64 g, K=1024.
// Grid: 512 blocks x 4 waves. Twin waves (g-halves) in a block share A rows
// (second read hits L1/L2), so A crosses HBM exactly once here (64 MB).
// Register ping-pong prefetch; compiler pipelines freely (no barriers).
// ---------------------------------------------------------------------------
__global__ __launch_bounds__(256, 2) void k_agg(const float* __restrict__ A,
                                                const unsigned short* __restrict__ Yt,
                                                const float* __restrict__ d,
                                                float* __restrict__ out) {
  int t = threadIdx.x;
  int wave = t >> 6, lane = t & 63;
  int quad = lane >> 4, l16 = lane & 15;
  int b   = blockIdx.x >> 5;
  int rem = blockIdx.x & 31;
  int ntile = rem * 2 + (wave >> 1);
  int gh    = wave & 1;
  int n0 = ntile * 16;
  int g0 = gh * 64;

  const float* Ap = A + (size_t)(b * NN + n0 + l16) * NN + quad * 8;
  const unsigned short* Yp[4];
#pragma unroll
  for (int ct = 0; ct < 4; ++ct)
    Yp[ct] = Yt + (size_t)(b * 128 + g0 + ct * 16 + l16) * NN + quad * 8;

  f32x4 acc[4];
#pragma unroll
  for (int ct = 0; ct < 4; ++ct) acc[ct] = (f32x4){0.f, 0.f, 0.f, 0.f};

  // prefetch k-tile 0
  float4 a0 = *(const float4*)(Ap);
  float4 a1 = *(const float4*)(Ap + 4);
  bf16x8 y[4];
#pragma unroll
  for (int ct = 0; ct < 4; ++ct) y[ct] = *(const bf16x8*)(Yp[ct]);

#pragma unroll 2
  for (int k0 = 0; k0 < NN; k0 += 32) {
    float4 na0, na1;
    bf16x8 ny[4];
    if (k0 + 32 < NN) {
      na0 = *(const float4*)(Ap + k0 + 32);
      na1 = *(const float4*)(Ap + k0 + 36);
#pragma unroll
      for (int ct = 0; ct < 4; ++ct)
        ny[ct] = *(const bf16x8*)(Yp[ct] + k0 + 32);
    }
    bf16x8 af = cvt8(a0, a1);
#pragma unroll
    for (int ct = 0; ct < 4; ++ct)
      acc[ct] = __builtin_amdgcn_mfma_f32_16x16x32_bf16(af, y[ct], acc[ct], 0, 0, 0);
    a0 = na0; a1 = na1;
#pragma unroll
    for (int ct = 0; ct < 4; ++ct) y[ct] = ny[ct];
  }

  // epilogue: out[n,g] = d[n] * (acc + Yt[g][n]); C/D: row = quad*4+reg, col = l16
  int nb = n0 + quad * 4;
  float4 d4 = *(const float4*)(d + b * NN + nb);
#pragma unroll
  for (int ct = 0; ct < 4; ++ct) {
    int g = g0 + ct * 16 + l16;
    ushort4 yv = *(const ushort4*)(Yt + (size_t)(b * 128 + g) * NN + nb);
    float* op = out + ((size_t)(b * NN + nb) * FF + g);
    op[0 * FF] = d4.x * (acc[ct][0] + bf2f(yv.x));
    op[1 * FF] = d4.y * (acc[ct][1] + bf2f(yv.y));
    op[2 * FF] = d4.z * (acc[ct][2] + bf2f(yv.z));
    op[3 * FF] = d4.w * (acc[ct][3] + bf2f(yv.w));
  }
}

// ---------------------------------------------------------------------------
extern "C" void kernel_launch(void* const* d_in, const int* in_sizes, int n_in,
                              void* d_out, int out_size, void* d_ws, size_t ws_size,
                              hipStream_t stream) {
  const float* X = (const float*)d_in[0];  // [16,1024,128]
  const float* A = (const float*)d_in[1];  // [16,1024,1024]
  const float* W = (const float*)d_in[2];  // [128,128]
  float* out = (float*)d_out;              // [16,1024,128]

  char* ws = (char*)d_ws;
  float*          dinv = (float*)ws;                              // 64 KB
  unsigned short* Wt   = (unsigned short*)(ws + 65536);           // 32 KB
  unsigned short* Yt   = (unsigned short*)(ws + 65536 + 32768);   // 4 MB  [b][g][m]

  k_deg<<<dim3(4096 + 64), dim3(256), 0, stream>>>(A, W, dinv, Wt);
  k_xw <<<dim3(256),       dim3(256), 0, stream>>>(X, Wt, dinv, Yt);
  k_agg<<<dim3(512),       dim3(256), 0, stream>>>(A, Yt, dinv, out);
}